// Round 10
// baseline (541.048 us; speedup 1.0000x reference)
//
#include <hip/hip_runtime.h>
#include <math.h>

#define TPB 256
#define FTPB 512     // fine-pass threads (one per superbucket node)
#define D_IN 16
#define D_OUT 32
#define NUM_K 8
#define WPAD 516     // kernel-h stride in LDS for sW
#define SBN_LOG 9    // 512 nodes per superbucket
#define SBN 512
#define CT 4096      // coarse tile (edges per block)
#define EPT 16       // edges per thread in coarse pass

// ---------------- init: bucket bases + cursors ----------------
__global__ void k_init(int* __restrict__ sbase, int* __restrict__ scursor,
                       int* __restrict__ sbcnt, int cap, int strided) {
    int t = threadIdx.x;
    if (t < 257) sbase[t] = strided ? t * cap : 0;
    if (t < 256) { scursor[t] = 0; sbcnt[t] = 0; }
}

// ---------------- dense-mode superbucket counting (fallback) ----------------

__global__ void k_sbhist(const int* __restrict__ dst, int* __restrict__ sbcnt, int E) {
    __shared__ int h[256];
    for (int i = threadIdx.x; i < 256; i += TPB) h[i] = 0;
    __syncthreads();
    int stride = gridDim.x * TPB;
    for (int e = blockIdx.x * TPB + threadIdx.x; e < E; e += stride)
        atomicAdd(&h[dst[e] >> SBN_LOG], 1);
    __syncthreads();
    for (int i = threadIdx.x; i < 256; i += TPB)
        if (h[i]) atomicAdd(&sbcnt[i], h[i]);
}

__global__ void k_sbscan(const int* __restrict__ sbcnt, int* __restrict__ sbase, int nsb) {
    __shared__ int sd[256];
    int t = threadIdx.x;
    int own = (t < nsb) ? sbcnt[t] : 0;
    sd[t] = own;
    __syncthreads();
    for (int s = 1; s < 256; s <<= 1) {
        int add = (t >= s) ? sd[t - s] : 0;
        __syncthreads();
        sd[t] += add;
        __syncthreads();
    }
    sbase[t] = sd[t] - own;   // exclusive
}

// -------- coarse pass: LDS radix-partition edges into superbuckets --------
// tmp record: x = src(17b) | dst_local(9b)<<17 ; y = packed attr (30b)
__global__ __launch_bounds__(TPB) void k_coarse(
        const int* __restrict__ src, const int* __restrict__ dst,
        const float* __restrict__ attr, const int* __restrict__ sbase,
        int* __restrict__ scursor, uint2* __restrict__ tmp, int E, int nsb) {
    __shared__ int hist[256];
    __shared__ int base[256];
    __shared__ int goff[256];
    __shared__ __align__(16) uint2 stage[CT];     // 32 KB
    __shared__ unsigned char ssb[CT];             // 4 KB

    int tile0 = blockIdx.x * CT;
    for (int i = threadIdx.x; i < 256; i += TPB) hist[i] = 0;
    __syncthreads();

    unsigned rx[EPT], ry[EPT];
    int rk[EPT], sbv[EPT];
#pragma unroll
    for (int i = 0; i < EPT; i++) {
        int e = tile0 + i * TPB + threadIdx.x;
        sbv[i] = -1;
        if (e < E) {
            int s = src[e], d = dst[e];
            float f0 = attr[3 * e + 0], f1 = attr[3 * e + 1], f2 = attr[3 * e + 2];
            int q0 = min((int)(f0 * 1024.f), 1023);
            int q1 = min((int)(f1 * 1024.f), 1023);
            int q2 = min((int)(f2 * 1024.f), 1023);
            int sb = d >> SBN_LOG;
            rx[i] = (unsigned)s | ((unsigned)(d & (SBN - 1)) << 17);
            ry[i] = (unsigned)q0 | ((unsigned)q1 << 10) | ((unsigned)q2 << 20);
            rk[i] = atomicAdd(&hist[sb], 1);
            sbv[i] = sb;
        }
    }
    __syncthreads();

    int t = threadIdx.x;
    int cntv = hist[t];
    base[t] = cntv;
    __syncthreads();
    for (int s = 1; s < 256; s <<= 1) {
        int add = (t >= s) ? base[t - s] : 0;
        __syncthreads();
        base[t] += add;
        __syncthreads();
    }
    int excl = base[t] - cntv;
    if (t < nsb && cntv > 0) goff[t] = sbase[t] + atomicAdd(&scursor[t], cntv);
    __syncthreads();
    base[t] = excl;
    __syncthreads();

#pragma unroll
    for (int i = 0; i < EPT; i++) {
        if (sbv[i] >= 0) {
            int slot = base[sbv[i]] + rk[i];
            stage[slot] = make_uint2(rx[i], ry[i]);
            ssb[slot] = (unsigned char)sbv[i];
        }
    }
    __syncthreads();

    int tileCount = min(E - tile0, CT);
    for (int j = threadIdx.x; j < tileCount; j += TPB) {
        int sb = ssb[j];
        tmp[goff[sb] + (j - base[sb])] = stage[j];
    }
}

// -------- fine pass: per-superbucket LDS count + wave-shuffle scan + scatter --------
__global__ __launch_bounds__(FTPB) void k_fine2(
        const uint2* __restrict__ tmp, const int* __restrict__ sbase,
        const int* __restrict__ scursor, int* __restrict__ rs, int* __restrict__ re,
        uint2* __restrict__ rec, int N) {
    __shared__ int hist[SBN];
    __shared__ int wsum[8], woff[8];
    int b = blockIdx.x;
    int lo = sbase[b];
    int hi = lo + scursor[b];
    int t = threadIdx.x;
    hist[t] = 0;
    __syncthreads();
    for (int p = lo + t; p < hi; p += FTPB)
        atomicAdd(&hist[(tmp[p].x >> 17) & (SBN - 1)], 1);
    __syncthreads();
    int own = hist[t];

    int lane = t & 63, w = t >> 6;
    int inc = own;
#pragma unroll
    for (int s = 1; s < 64; s <<= 1) {
        int u = __shfl_up(inc, s);
        if (lane >= s) inc += u;
    }
    if (lane == 63) wsum[w] = inc;
    __syncthreads();
    if (t < 8) {
        int x = wsum[t], ex = x;
#pragma unroll
        for (int s = 1; s < 8; s <<= 1) {
            int u = __shfl_up(ex, s);
            if (t >= s) ex += u;
        }
        woff[t] = ex - x;
    }
    __syncthreads();
    int incl = inc + woff[w];
    int excl = incl - own;

    int n = (b << SBN_LOG) + t;
    if (n < N) { rs[n] = lo + excl; re[n] = lo + incl; }
    hist[t] = lo + excl;
    __syncthreads();
    for (int p = lo + t; p < hi; p += FTPB) {
        uint2 r = tmp[p];
        int dl = (int)((r.x >> 17) & (SBN - 1));
        int slot = atomicAdd(&hist[dl], 1);
        rec[slot] = make_uint2(r.x & 0x1FFFFu, r.y);
    }
}

// ---------------- single-pass fallback pipeline ----------------

__global__ void k_zero(int* __restrict__ cnt, int N) {
    int i = blockIdx.x * TPB + threadIdx.x;
    if (i < N) cnt[i] = 0;
}

__global__ void k_hist(const int* __restrict__ dst, int* __restrict__ cnt, int E) {
    int e = blockIdx.x * TPB + threadIdx.x;
    if (e < E) atomicAdd(&cnt[dst[e]], 1);
}

__global__ void k_scan_a(const int* __restrict__ cnt, int* __restrict__ bsum, int N) {
    __shared__ int sd[TPB];
    int i = blockIdx.x * TPB + threadIdx.x;
    sd[threadIdx.x] = (i < N) ? cnt[i] : 0;
    __syncthreads();
    for (int s = TPB / 2; s > 0; s >>= 1) {
        if (threadIdx.x < s) sd[threadIdx.x] += sd[threadIdx.x + s];
        __syncthreads();
    }
    if (threadIdx.x == 0) bsum[blockIdx.x] = sd[0];
}

__global__ void k_scan_b(const int* __restrict__ bsum, int* __restrict__ boff, int nb) {
    __shared__ int sd[512];
    int t = threadIdx.x;
    int own = (t < nb) ? bsum[t] : 0;
    sd[t] = own;
    __syncthreads();
    for (int s = 1; s < 512; s <<= 1) {
        int a = sd[t];
        int b = (t >= s) ? sd[t - s] : 0;
        __syncthreads();
        sd[t] = a + b;
        __syncthreads();
    }
    if (t < nb) boff[t] = sd[t] - own;
}

__global__ void k_scan_c(const int* __restrict__ cnt, const int* __restrict__ boff,
                         int* __restrict__ rs, int* __restrict__ re, int N) {
    __shared__ int sd[TPB];
    int t = threadIdx.x;
    int i = blockIdx.x * TPB + t;
    int v = (i < N) ? cnt[i] : 0;
    sd[t] = v;
    __syncthreads();
    for (int s = 1; s < TPB; s <<= 1) {
        int a = sd[t];
        int b = (t >= s) ? sd[t - s] : 0;
        __syncthreads();
        sd[t] = a + b;
        __syncthreads();
    }
    int excl = sd[t] - v + boff[blockIdx.x];
    if (i < N) { rs[i] = excl; re[i] = excl; }
}

__global__ void k_scatter(const int* __restrict__ src, const int* __restrict__ dst,
                          const float* __restrict__ attr, int* __restrict__ re,
                          uint2* __restrict__ rec, int E) {
    int e = blockIdx.x * TPB + threadIdx.x;
    if (e < E) {
        float f0 = attr[3 * e + 0], f1 = attr[3 * e + 1], f2 = attr[3 * e + 2];
        int q0 = min((int)(f0 * 1024.f), 1023);
        int q1 = min((int)(f1 * 1024.f), 1023);
        int q2 = min((int)(f2 * 1024.f), 1023);
        unsigned pk = (unsigned)q0 | ((unsigned)q1 << 10) | ((unsigned)q2 << 20);
        int pos = atomicAdd(&re[dst[e]], 1);
        rec[pos] = make_uint2((unsigned)src[e], pk);
    }
}

// ---------------- main aggregation: 16 lanes per node (R8-proven form) ----------------
// sub = lane-in-node (0..15), grp = sub>>3 (edge parity), h = sub&7 (spline kernel).
// Edge loop: SOFTWARE-PIPELINED (rec 2-ahead, x 1-ahead). DO NOT restructure:
// R6/R7 (unroll w/o prefetch) and R9 (node-pairing, +reg pressure) both regressed.

__global__ __launch_bounds__(TPB, 4) void k_agg(
    const float* __restrict__ x, const float* __restrict__ W,
    const float* __restrict__ Wr, const float* __restrict__ bias,
    const int* __restrict__ rs, const int* __restrict__ re,
    const uint2* __restrict__ rec,
    float* __restrict__ out, float* __restrict__ partials, int N) {

    __shared__ __align__(16) float sW[NUM_K * WPAD];   // ~16.5 KB
    __shared__ __align__(16) float sWr[D_IN * D_OUT];  // 2 KB
    __shared__ float sB[D_OUT];
    __shared__ float4 sStats[4][16];

    for (int idx = threadIdx.x; idx < NUM_K * D_IN * D_OUT; idx += TPB) {
        int k = idx >> 9, rem = idx & 511, i = rem >> 5, c = rem & 31;
        sW[k * WPAD + i * 32 + c] = W[idx];
    }
    for (int idx = threadIdx.x; idx < D_IN * D_OUT; idx += TPB) sWr[idx] = Wr[idx];
    if (threadIdx.x < D_OUT) sB[threadIdx.x] = bias[threadIdx.x];
    __syncthreads();

    int t   = blockIdx.x * TPB + threadIdx.x;
    int n   = t >> 4;
    int sub = t & 15;
    int grp = sub >> 3;
    int h   = sub & 7;
    bool valid = n < N;

    // lane-constant basis coefficients: sel = (bit ? f : 1-f), f = (q+0.5)/1024
    const float INV = 1.0f / 1024.0f, HLF = 1.0f / 2048.0f;
    float sc0 = (h & 1) ? INV : -INV, cc0 = (h & 1) ? HLF : 1.f - HLF;
    float sc1 = (h & 2) ? INV : -INV, cc1 = (h & 2) ? HLF : 1.f - HLF;
    float sc2 = (h & 4) ? INV : -INV, cc2 = (h & 4) ? HLF : 1.f - HLF;

    float4 g0 = {0,0,0,0}, g1 = {0,0,0,0}, g2 = {0,0,0,0}, g3 = {0,0,0,0};
    int deg = 0;
    if (valid) {
        int p0 = rs[n], p1 = re[n];
        deg = p1 - p0;
        int p = p0 + grp;
        if (p < p1) {
            int last = p1 - 1;
            // software pipeline: r=current rec, rn=next rec, xq=current x row
            uint2 r  = rec[p];
            uint2 rn = rec[min(p + 2, last)];
            const float4* xr = (const float4*)x + (size_t)r.x * 4;
            float4 xq0 = xr[0], xq1 = xr[1], xq2 = xr[2], xq3 = xr[3];
            for (; p < p1; p += 2) {
                uint2 rnn = rec[min(p + 4, last)];
                const float4* xnr = (const float4*)x + (size_t)rn.x * 4;
                float4 xn0 = xnr[0], xn1 = xnr[1], xn2 = xnr[2], xn3 = xnr[3];
                float q0v = (float)(r.y & 1023u);
                float q1v = (float)((r.y >> 10) & 1023u);
                float q2v = (float)((r.y >> 20) & 1023u);
                float bs = fmaf(q0v, sc0, cc0) * fmaf(q1v, sc1, cc1) * fmaf(q2v, sc2, cc2);
                g0.x = fmaf(bs, xq0.x, g0.x); g0.y = fmaf(bs, xq0.y, g0.y);
                g0.z = fmaf(bs, xq0.z, g0.z); g0.w = fmaf(bs, xq0.w, g0.w);
                g1.x = fmaf(bs, xq1.x, g1.x); g1.y = fmaf(bs, xq1.y, g1.y);
                g1.z = fmaf(bs, xq1.z, g1.z); g1.w = fmaf(bs, xq1.w, g1.w);
                g2.x = fmaf(bs, xq2.x, g2.x); g2.y = fmaf(bs, xq2.y, g2.y);
                g2.z = fmaf(bs, xq2.z, g2.z); g2.w = fmaf(bs, xq2.w, g2.w);
                g3.x = fmaf(bs, xq3.x, g3.x); g3.y = fmaf(bs, xq3.y, g3.y);
                g3.z = fmaf(bs, xq3.z, g3.z); g3.w = fmaf(bs, xq3.w, g3.w);
                r = rn; rn = rnn;
                xq0 = xn0; xq1 = xn1; xq2 = xn2; xq3 = xn3;
            }
        }
    }

    // combine the two edge-groups (lanes sub and sub^8 share kernel h)
    g0.x += __shfl_xor(g0.x, 8); g0.y += __shfl_xor(g0.y, 8);
    g0.z += __shfl_xor(g0.z, 8); g0.w += __shfl_xor(g0.w, 8);
    g1.x += __shfl_xor(g1.x, 8); g1.y += __shfl_xor(g1.y, 8);
    g1.z += __shfl_xor(g1.z, 8); g1.w += __shfl_xor(g1.w, 8);
    g2.x += __shfl_xor(g2.x, 8); g2.y += __shfl_xor(g2.y, 8);
    g2.z += __shfl_xor(g2.z, 8); g2.w += __shfl_xor(g2.w, 8);
    g3.x += __shfl_xor(g3.x, 8); g3.y += __shfl_xor(g3.y, 8);
    g3.z += __shfl_xor(g3.z, 8); g3.w += __shfl_xor(g3.w, 8);

    // contraction: this lane computes channels [16*grp, 16*grp+16) for kernel h
    float4 o0 = {0,0,0,0}, o1 = {0,0,0,0}, o2 = {0,0,0,0}, o3 = {0,0,0,0};
    const float* wbase = sW + h * WPAD + grp * 16;
#define CONTRACT1(gv, i) { \
        const float4* wr_ = (const float4*)(wbase + (i) * 32); \
        float4 w0 = wr_[0], w1 = wr_[1], w2 = wr_[2], w3 = wr_[3]; \
        o0.x = fmaf(gv, w0.x, o0.x); o0.y = fmaf(gv, w0.y, o0.y); \
        o0.z = fmaf(gv, w0.z, o0.z); o0.w = fmaf(gv, w0.w, o0.w); \
        o1.x = fmaf(gv, w1.x, o1.x); o1.y = fmaf(gv, w1.y, o1.y); \
        o1.z = fmaf(gv, w1.z, o1.z); o1.w = fmaf(gv, w1.w, o1.w); \
        o2.x = fmaf(gv, w2.x, o2.x); o2.y = fmaf(gv, w2.y, o2.y); \
        o2.z = fmaf(gv, w2.z, o2.z); o2.w = fmaf(gv, w2.w, o2.w); \
        o3.x = fmaf(gv, w3.x, o3.x); o3.y = fmaf(gv, w3.y, o3.y); \
        o3.z = fmaf(gv, w3.z, o3.z); o3.w = fmaf(gv, w3.w, o3.w); }
    CONTRACT1(g0.x,  0) CONTRACT1(g0.y,  1) CONTRACT1(g0.z,  2) CONTRACT1(g0.w,  3)
    CONTRACT1(g1.x,  4) CONTRACT1(g1.y,  5) CONTRACT1(g1.z,  6) CONTRACT1(g1.w,  7)
    CONTRACT1(g2.x,  8) CONTRACT1(g2.y,  9) CONTRACT1(g2.z, 10) CONTRACT1(g2.w, 11)
    CONTRACT1(g3.x, 12) CONTRACT1(g3.y, 13) CONTRACT1(g3.z, 14) CONTRACT1(g3.w, 15)
#undef CONTRACT1

    float inv = 1.f / (float)(deg > 0 ? deg : 1);
    o0.x *= inv; o0.y *= inv; o0.z *= inv; o0.w *= inv;
    o1.x *= inv; o1.y *= inv; o1.z *= inv; o1.w *= inv;
    o2.x *= inv; o2.y *= inv; o2.z *= inv; o2.w *= inv;
    o3.x *= inv; o3.y *= inv; o3.z *= inv; o3.w *= inv;

    // reduce-scatter across the 8 h-lanes: 16 -> 8 -> 4 -> 2 channels
    bool hi4 = (h & 4) != 0;
    float4 k0, k1, s0, s1;
    k0 = hi4 ? o2 : o0; k1 = hi4 ? o3 : o1;
    s0 = hi4 ? o0 : o2; s1 = hi4 ? o1 : o3;
    k0.x += __shfl_xor(s0.x, 4); k0.y += __shfl_xor(s0.y, 4);
    k0.z += __shfl_xor(s0.z, 4); k0.w += __shfl_xor(s0.w, 4);
    k1.x += __shfl_xor(s1.x, 4); k1.y += __shfl_xor(s1.y, 4);
    k1.z += __shfl_xor(s1.z, 4); k1.w += __shfl_xor(s1.w, 4);

    bool hi2 = (h & 2) != 0;
    float4 m0 = hi2 ? k1 : k0;
    float4 sm = hi2 ? k0 : k1;
    m0.x += __shfl_xor(sm.x, 2); m0.y += __shfl_xor(sm.y, 2);
    m0.z += __shfl_xor(sm.z, 2); m0.w += __shfl_xor(sm.w, 2);

    bool hi1 = (h & 1) != 0;
    float e0 = hi1 ? m0.z : m0.x;
    float e1 = hi1 ? m0.w : m0.y;
    float sa = hi1 ? m0.x : m0.z;
    float sb_ = hi1 ? m0.y : m0.w;
    e0 += __shfl_xor(sa, 1);
    e1 += __shfl_xor(sb_, 1);
    // lane now owns channels c0 = 2*sub, c0+1

    int c0 = 2 * sub;
    if (valid) {
        const float4* xr = (const float4*)x + (size_t)n * 4;
        float4 r0 = xr[0], r1 = xr[1], r2 = xr[2], r3 = xr[3];
#define ROOT1(xv, i) { \
            float2 w = *(const float2*)(sWr + (i) * 32 + c0); \
            e0 = fmaf(xv, w.x, e0); e1 = fmaf(xv, w.y, e1); }
        ROOT1(r0.x,  0) ROOT1(r0.y,  1) ROOT1(r0.z,  2) ROOT1(r0.w,  3)
        ROOT1(r1.x,  4) ROOT1(r1.y,  5) ROOT1(r1.z,  6) ROOT1(r1.w,  7)
        ROOT1(r2.x,  8) ROOT1(r2.y,  9) ROOT1(r2.z, 10) ROOT1(r2.w, 11)
        ROOT1(r3.x, 12) ROOT1(r3.y, 13) ROOT1(r3.z, 14) ROOT1(r3.w, 15)
#undef ROOT1
    }

    float2 bb = *(const float2*)(sB + c0);
    e0 += bb.x; e1 += bb.y;
    e0 = e0 > 0.f ? e0 : (__expf(e0) - 1.f);
    e1 = e1 > 0.f ? e1 : (__expf(e1) - 1.f);

    if (valid) *(float2*)(out + (size_t)n * D_OUT + c0) = make_float2(e0, e1);

    // block-level batch stats (NO global atomics)
    float ss0 = valid ? e0 : 0.f, ss1 = valid ? e1 : 0.f;
    float q0 = ss0 * ss0, q1 = ss1 * ss1;
    ss0 += __shfl_xor(ss0, 16); ss1 += __shfl_xor(ss1, 16);
    q0  += __shfl_xor(q0, 16);  q1  += __shfl_xor(q1, 16);
    ss0 += __shfl_xor(ss0, 32); ss1 += __shfl_xor(ss1, 32);
    q0  += __shfl_xor(q0, 32);  q1  += __shfl_xor(q1, 32);
    if ((threadIdx.x & 63) < 16)
        sStats[threadIdx.x >> 6][sub] = make_float4(ss0, ss1, q0, q1);
    __syncthreads();
    if (threadIdx.x < 64) {
        const float* sf = (const float*)sStats;
        float v = sf[threadIdx.x] + sf[64 + threadIdx.x] +
                  sf[128 + threadIdx.x] + sf[192 + threadIdx.x];
        int ssub = threadIdx.x >> 2, comp = threadIdx.x & 3;
        int col = 2 * ssub + (comp & 1) + 32 * (comp >> 1);  // 0..31 sum, 32..63 sumsq
        partials[(size_t)blockIdx.x * 64 + col] = v;
    }
}

// ---------------- merged stats reduction + BN coefficient computation ----------------
// single block, 256 threads: 4 threads per column, strided over all partial rows

__global__ void k_bnfin(const float* __restrict__ partials, const float* __restrict__ gamma,
                        const float* __restrict__ beta, float* __restrict__ stats,
                        int nrows, int N) {
    __shared__ float sd[4][64];
    int col = threadIdx.x & 63, j = threadIdx.x >> 6;   // 256 threads: 4 strides x 64 cols
    float v = 0.f;
    for (int r = j; r < nrows; r += 4) v += partials[(size_t)r * 64 + col];
    sd[j][col] = v;
    __syncthreads();
    if (threadIdx.x < 32) {
        int c = threadIdx.x;
        float S = sd[0][c] + sd[1][c] + sd[2][c] + sd[3][c];
        float Q = sd[0][32 + c] + sd[1][32 + c] + sd[2][32 + c] + sd[3][32 + c];
        float mean = S / (float)N;
        float var  = Q / (float)N - mean * mean;
        float sc   = gamma[c] * rsqrtf(var + 1e-5f);
        stats[c]      = sc;                    // scale
        stats[32 + c] = beta[c] - mean * sc;   // shift
    }
}

__global__ void k_bnapply(float* __restrict__ out, const float* __restrict__ stats, int total4) {
    int i = blockIdx.x * TPB + threadIdx.x;
    if (i < total4) {
        float4 v = ((float4*)out)[i];
        int c0 = (i * 4) & (D_OUT - 1);
        v.x = v.x * stats[c0 + 0] + stats[32 + c0 + 0];
        v.y = v.y * stats[c0 + 1] + stats[32 + c0 + 1];
        v.z = v.z * stats[c0 + 2] + stats[32 + c0 + 2];
        v.w = v.w * stats[c0 + 3] + stats[32 + c0 + 3];
        ((float4*)out)[i] = v;
    }
}

// ---------------- launcher ----------------

extern "C" void kernel_launch(void* const* d_in, const int* in_sizes, int n_in,
                              void* d_out, int out_size, void* d_ws, size_t ws_size,
                              hipStream_t stream) {
    const float* x     = (const float*)d_in[0];
    const int* eidx    = (const int*)d_in[1];
    const float* attr  = (const float*)d_in[2];
    const float* W     = (const float*)d_in[3];
    const float* Wr    = (const float*)d_in[4];
    const float* bias  = (const float*)d_in[5];
    const float* gamma = (const float*)d_in[6];
    const float* beta  = (const float*)d_in[7];
    float* out = (float*)d_out;

    const int N = in_sizes[0] / D_IN;
    const int E = in_sizes[1] / 2;
    const int* src = eidx;
    const int* dst = eidx + E;

    const int nb  = (N + TPB - 1) / TPB;
    const int gE  = (E + TPB - 1) / TPB;
    const int nsb = (N + SBN - 1) / SBN;
    const int nbAgg = (16 * N + TPB - 1) / TPB;   // 16 lanes per node
    const int gC  = (E + CT - 1) / CT;

    // fixed-capacity bucket windows: mean + >=8 sigma slack (binomial, P(overflow)~1e-15)
    int capBase = (E + nsb - 1) / nsb;
    int slack = capBase / 16 > 1024 ? capBase / 16 : 1024;
    int cap = capBase + slack;

    // workspace head
    int* rs          = (int*)d_ws;                     // N
    int* re          = rs + N;                         // N (single-path: also cursor)
    float* partials  = (float*)(re + N);               // nbAgg * 64
    float* stats     = partials + (size_t)nbAgg * 64;  // 64
    int* sbase       = (int*)(stats + 64);             // 257
    int* scursor     = sbase + 257;                    // 256
    int* sbcnt       = scursor + 256;                  // 256
    uintptr_t tail   = ((uintptr_t)(sbcnt + 256) + 15) & ~(uintptr_t)15;
    size_t headBytes = tail - (uintptr_t)d_ws;

    size_t recStr      = (size_t)nsb * cap;
    size_t needStrided = headBytes + 2 * recStr * 8;
    size_t needDense   = headBytes + 2 * (size_t)E * 8;
    size_t needSingle  = headBytes + (size_t)E * 8 + ((size_t)N + 2 * (size_t)nb) * 4;

    if (ws_size >= needStrided && nsb <= 256) {
        uint2* rec = (uint2*)tail;
        uint2* tmp = rec + recStr;
        k_init<<<1, 512, 0, stream>>>(sbase, scursor, sbcnt, cap, 1);
        k_coarse<<<gC, TPB, 0, stream>>>(src, dst, attr, sbase, scursor, tmp, E, nsb);
        k_fine2<<<nsb, FTPB, 0, stream>>>(tmp, sbase, scursor, rs, re, rec, N);
        k_agg<<<nbAgg, TPB, 0, stream>>>(x, W, Wr, bias, rs, re, rec, out, partials, N);
    } else if (ws_size >= needDense && nsb <= 256) {
        uint2* rec = (uint2*)tail;
        uint2* tmp = rec + E;
        k_init<<<1, 512, 0, stream>>>(sbase, scursor, sbcnt, cap, 0);
        int gH = min(1024, gE);
        k_sbhist<<<gH, TPB, 0, stream>>>(dst, sbcnt, E);
        k_sbscan<<<1, 256, 0, stream>>>(sbcnt, sbase, nsb);
        k_coarse<<<gC, TPB, 0, stream>>>(src, dst, attr, sbase, scursor, tmp, E, nsb);
        k_fine2<<<nsb, FTPB, 0, stream>>>(tmp, sbase, scursor, rs, re, rec, N);
        k_agg<<<nbAgg, TPB, 0, stream>>>(x, W, Wr, bias, rs, re, rec, out, partials, N);
    } else if (ws_size >= needSingle && nb <= 512) {
        uint2* rec = (uint2*)tail;
        int* cnt   = (int*)(rec + E);
        int* bsum  = cnt + N;
        int* boff  = bsum + nb;
        k_zero<<<nb, TPB, 0, stream>>>(cnt, N);
        k_hist<<<gE, TPB, 0, stream>>>(dst, cnt, E);
        k_scan_a<<<nb, TPB, 0, stream>>>(cnt, bsum, N);
        k_scan_b<<<1, 512, 0, stream>>>(bsum, boff, nb);
        k_scan_c<<<nb, TPB, 0, stream>>>(cnt, boff, rs, re, N);
        k_scatter<<<gE, TPB, 0, stream>>>(src, dst, attr, re, rec, E);
        k_agg<<<nbAgg, TPB, 0, stream>>>(x, W, Wr, bias, rs, re, rec, out, partials, N);
    }

    k_bnfin<<<1, 256, 0, stream>>>(partials, gamma, beta, stats, nbAgg, N);
    int total4 = N * D_OUT / 4;
    k_bnapply<<<(total4 + TPB - 1) / TPB, TPB, 0, stream>>>(out, stats, total4);
}

// Round 11
// 192.434 us; speedup vs baseline: 2.8116x; 2.8116x over previous
//
#include <hip/hip_runtime.h>
#include <math.h>

#define TPB 256
#define FTPB 512     // fine-pass threads (one per superbucket node)
#define D_IN 16
#define D_OUT 32
#define NUM_K 8
#define WPAD 516     // kernel-h stride in LDS for sW
#define SBN_LOG 9    // 512 nodes per superbucket
#define SBN 512
#define CT 4096      // coarse tile (edges per block)
#define EPT 16       // edges per thread in coarse pass

// ---------------- init: bucket bases + cursors ----------------
__global__ void k_init(int* __restrict__ sbase, int* __restrict__ scursor,
                       int* __restrict__ sbcnt, int cap, int strided) {
    int t = threadIdx.x;
    if (t < 257) sbase[t] = strided ? t * cap : 0;
    if (t < 256) { scursor[t] = 0; sbcnt[t] = 0; }
}

// ---------------- dense-mode superbucket counting (fallback) ----------------

__global__ void k_sbhist(const int* __restrict__ dst, int* __restrict__ sbcnt, int E) {
    __shared__ int h[256];
    for (int i = threadIdx.x; i < 256; i += TPB) h[i] = 0;
    __syncthreads();
    int stride = gridDim.x * TPB;
    for (int e = blockIdx.x * TPB + threadIdx.x; e < E; e += stride)
        atomicAdd(&h[dst[e] >> SBN_LOG], 1);
    __syncthreads();
    for (int i = threadIdx.x; i < 256; i += TPB)
        if (h[i]) atomicAdd(&sbcnt[i], h[i]);
}

__global__ void k_sbscan(const int* __restrict__ sbcnt, int* __restrict__ sbase, int nsb) {
    __shared__ int sd[256];
    int t = threadIdx.x;
    int own = (t < nsb) ? sbcnt[t] : 0;
    sd[t] = own;
    __syncthreads();
    for (int s = 1; s < 256; s <<= 1) {
        int add = (t >= s) ? sd[t - s] : 0;
        __syncthreads();
        sd[t] += add;
        __syncthreads();
    }
    sbase[t] = sd[t] - own;   // exclusive
}

// -------- coarse pass: LDS radix-partition edges into superbuckets --------
// tmp record: x = src(17b) | dst_local(9b)<<17 ; y = packed attr (30b)
__global__ __launch_bounds__(TPB) void k_coarse(
        const int* __restrict__ src, const int* __restrict__ dst,
        const float* __restrict__ attr, const int* __restrict__ sbase,
        int* __restrict__ scursor, uint2* __restrict__ tmp, int E, int nsb) {
    __shared__ int hist[256];
    __shared__ int base[256];
    __shared__ int goff[256];
    __shared__ __align__(16) uint2 stage[CT];     // 32 KB
    __shared__ unsigned char ssb[CT];             // 4 KB

    int tile0 = blockIdx.x * CT;
    for (int i = threadIdx.x; i < 256; i += TPB) hist[i] = 0;
    __syncthreads();

    unsigned rx[EPT], ry[EPT];
    int rk[EPT], sbv[EPT];
#pragma unroll
    for (int i = 0; i < EPT; i++) {
        int e = tile0 + i * TPB + threadIdx.x;
        sbv[i] = -1;
        if (e < E) {
            int s = src[e], d = dst[e];
            float f0 = attr[3 * e + 0], f1 = attr[3 * e + 1], f2 = attr[3 * e + 2];
            int q0 = min((int)(f0 * 1024.f), 1023);
            int q1 = min((int)(f1 * 1024.f), 1023);
            int q2 = min((int)(f2 * 1024.f), 1023);
            int sb = d >> SBN_LOG;
            rx[i] = (unsigned)s | ((unsigned)(d & (SBN - 1)) << 17);
            ry[i] = (unsigned)q0 | ((unsigned)q1 << 10) | ((unsigned)q2 << 20);
            rk[i] = atomicAdd(&hist[sb], 1);
            sbv[i] = sb;
        }
    }
    __syncthreads();

    int t = threadIdx.x;
    int cntv = hist[t];
    base[t] = cntv;
    __syncthreads();
    for (int s = 1; s < 256; s <<= 1) {
        int add = (t >= s) ? base[t - s] : 0;
        __syncthreads();
        base[t] += add;
        __syncthreads();
    }
    int excl = base[t] - cntv;
    if (t < nsb && cntv > 0) goff[t] = sbase[t] + atomicAdd(&scursor[t], cntv);
    __syncthreads();
    base[t] = excl;
    __syncthreads();

#pragma unroll
    for (int i = 0; i < EPT; i++) {
        if (sbv[i] >= 0) {
            int slot = base[sbv[i]] + rk[i];
            stage[slot] = make_uint2(rx[i], ry[i]);
            ssb[slot] = (unsigned char)sbv[i];
        }
    }
    __syncthreads();

    int tileCount = min(E - tile0, CT);
    for (int j = threadIdx.x; j < tileCount; j += TPB) {
        int sb = ssb[j];
        tmp[goff[sb] + (j - base[sb])] = stage[j];
    }
}

// -------- fine pass: per-superbucket LDS count + wave-shuffle scan + scatter --------
__global__ __launch_bounds__(FTPB) void k_fine2(
        const uint2* __restrict__ tmp, const int* __restrict__ sbase,
        const int* __restrict__ scursor, int* __restrict__ rs, int* __restrict__ re,
        uint2* __restrict__ rec, int N) {
    __shared__ int hist[SBN];
    __shared__ int wsum[8], woff[8];
    int b = blockIdx.x;
    int lo = sbase[b];
    int hi = lo + scursor[b];
    int t = threadIdx.x;
    hist[t] = 0;
    __syncthreads();
    for (int p = lo + t; p < hi; p += FTPB)
        atomicAdd(&hist[(tmp[p].x >> 17) & (SBN - 1)], 1);
    __syncthreads();
    int own = hist[t];

    int lane = t & 63, w = t >> 6;
    int inc = own;
#pragma unroll
    for (int s = 1; s < 64; s <<= 1) {
        int u = __shfl_up(inc, s);
        if (lane >= s) inc += u;
    }
    if (lane == 63) wsum[w] = inc;
    __syncthreads();
    if (t < 8) {
        int x = wsum[t], ex = x;
#pragma unroll
        for (int s = 1; s < 8; s <<= 1) {
            int u = __shfl_up(ex, s);
            if (t >= s) ex += u;
        }
        woff[t] = ex - x;
    }
    __syncthreads();
    int incl = inc + woff[w];
    int excl = incl - own;

    int n = (b << SBN_LOG) + t;
    if (n < N) { rs[n] = lo + excl; re[n] = lo + incl; }
    hist[t] = lo + excl;
    __syncthreads();
    for (int p = lo + t; p < hi; p += FTPB) {
        uint2 r = tmp[p];
        int dl = (int)((r.x >> 17) & (SBN - 1));
        int slot = atomicAdd(&hist[dl], 1);
        rec[slot] = make_uint2(r.x & 0x1FFFFu, r.y);
    }
}

// ---------------- single-pass fallback pipeline ----------------

__global__ void k_zero(int* __restrict__ cnt, int N) {
    int i = blockIdx.x * TPB + threadIdx.x;
    if (i < N) cnt[i] = 0;
}

__global__ void k_hist(const int* __restrict__ dst, int* __restrict__ cnt, int E) {
    int e = blockIdx.x * TPB + threadIdx.x;
    if (e < E) atomicAdd(&cnt[dst[e]], 1);
}

__global__ void k_scan_a(const int* __restrict__ cnt, int* __restrict__ bsum, int N) {
    __shared__ int sd[TPB];
    int i = blockIdx.x * TPB + threadIdx.x;
    sd[threadIdx.x] = (i < N) ? cnt[i] : 0;
    __syncthreads();
    for (int s = TPB / 2; s > 0; s >>= 1) {
        if (threadIdx.x < s) sd[threadIdx.x] += sd[threadIdx.x + s];
        __syncthreads();
    }
    if (threadIdx.x == 0) bsum[blockIdx.x] = sd[0];
}

__global__ void k_scan_b(const int* __restrict__ bsum, int* __restrict__ boff, int nb) {
    __shared__ int sd[512];
    int t = threadIdx.x;
    int own = (t < nb) ? bsum[t] : 0;
    sd[t] = own;
    __syncthreads();
    for (int s = 1; s < 512; s <<= 1) {
        int a = sd[t];
        int b = (t >= s) ? sd[t - s] : 0;
        __syncthreads();
        sd[t] = a + b;
        __syncthreads();
    }
    if (t < nb) boff[t] = sd[t] - own;
}

__global__ void k_scan_c(const int* __restrict__ cnt, const int* __restrict__ boff,
                         int* __restrict__ rs, int* __restrict__ re, int N) {
    __shared__ int sd[TPB];
    int t = threadIdx.x;
    int i = blockIdx.x * TPB + t;
    int v = (i < N) ? cnt[i] : 0;
    sd[t] = v;
    __syncthreads();
    for (int s = 1; s < TPB; s <<= 1) {
        int a = sd[t];
        int b = (t >= s) ? sd[t - s] : 0;
        __syncthreads();
        sd[t] = a + b;
        __syncthreads();
    }
    int excl = sd[t] - v + boff[blockIdx.x];
    if (i < N) { rs[i] = excl; re[i] = excl; }
}

__global__ void k_scatter(const int* __restrict__ src, const int* __restrict__ dst,
                          const float* __restrict__ attr, int* __restrict__ re,
                          uint2* __restrict__ rec, int E) {
    int e = blockIdx.x * TPB + threadIdx.x;
    if (e < E) {
        float f0 = attr[3 * e + 0], f1 = attr[3 * e + 1], f2 = attr[3 * e + 2];
        int q0 = min((int)(f0 * 1024.f), 1023);
        int q1 = min((int)(f1 * 1024.f), 1023);
        int q2 = min((int)(f2 * 1024.f), 1023);
        unsigned pk = (unsigned)q0 | ((unsigned)q1 << 10) | ((unsigned)q2 << 20);
        int pos = atomicAdd(&re[dst[e]], 1);
        rec[pos] = make_uint2((unsigned)src[e], pk);
    }
}

// ---------------- main aggregation: 16 lanes per node (R8-proven form) ----------------
// sub = lane-in-node (0..15), grp = sub>>3 (edge parity), h = sub&7 (spline kernel).
// Edge loop: SOFTWARE-PIPELINED (rec 2-ahead, x 1-ahead). DO NOT restructure:
// R6/R7 (unroll w/o prefetch) and R9 (node-pairing, +reg pressure) both regressed.

__global__ __launch_bounds__(TPB, 4) void k_agg(
    const float* __restrict__ x, const float* __restrict__ W,
    const float* __restrict__ Wr, const float* __restrict__ bias,
    const int* __restrict__ rs, const int* __restrict__ re,
    const uint2* __restrict__ rec,
    float* __restrict__ out, float* __restrict__ partials, int N) {

    __shared__ __align__(16) float sW[NUM_K * WPAD];   // ~16.5 KB
    __shared__ __align__(16) float sWr[D_IN * D_OUT];  // 2 KB
    __shared__ float sB[D_OUT];
    __shared__ float4 sStats[4][16];

    for (int idx = threadIdx.x; idx < NUM_K * D_IN * D_OUT; idx += TPB) {
        int k = idx >> 9, rem = idx & 511, i = rem >> 5, c = rem & 31;
        sW[k * WPAD + i * 32 + c] = W[idx];
    }
    for (int idx = threadIdx.x; idx < D_IN * D_OUT; idx += TPB) sWr[idx] = Wr[idx];
    if (threadIdx.x < D_OUT) sB[threadIdx.x] = bias[threadIdx.x];
    __syncthreads();

    int t   = blockIdx.x * TPB + threadIdx.x;
    int n   = t >> 4;
    int sub = t & 15;
    int grp = sub >> 3;
    int h   = sub & 7;
    bool valid = n < N;

    // lane-constant basis coefficients: sel = (bit ? f : 1-f), f = (q+0.5)/1024
    const float INV = 1.0f / 1024.0f, HLF = 1.0f / 2048.0f;
    float sc0 = (h & 1) ? INV : -INV, cc0 = (h & 1) ? HLF : 1.f - HLF;
    float sc1 = (h & 2) ? INV : -INV, cc1 = (h & 2) ? HLF : 1.f - HLF;
    float sc2 = (h & 4) ? INV : -INV, cc2 = (h & 4) ? HLF : 1.f - HLF;

    float4 g0 = {0,0,0,0}, g1 = {0,0,0,0}, g2 = {0,0,0,0}, g3 = {0,0,0,0};
    int deg = 0;
    if (valid) {
        int p0 = rs[n], p1 = re[n];
        deg = p1 - p0;
        int p = p0 + grp;
        if (p < p1) {
            int last = p1 - 1;
            // software pipeline: r=current rec, rn=next rec, xq=current x row
            uint2 r  = rec[p];
            uint2 rn = rec[min(p + 2, last)];
            const float4* xr = (const float4*)x + (size_t)r.x * 4;
            float4 xq0 = xr[0], xq1 = xr[1], xq2 = xr[2], xq3 = xr[3];
            for (; p < p1; p += 2) {
                uint2 rnn = rec[min(p + 4, last)];
                const float4* xnr = (const float4*)x + (size_t)rn.x * 4;
                float4 xn0 = xnr[0], xn1 = xnr[1], xn2 = xnr[2], xn3 = xnr[3];
                float q0v = (float)(r.y & 1023u);
                float q1v = (float)((r.y >> 10) & 1023u);
                float q2v = (float)((r.y >> 20) & 1023u);
                float bs = fmaf(q0v, sc0, cc0) * fmaf(q1v, sc1, cc1) * fmaf(q2v, sc2, cc2);
                g0.x = fmaf(bs, xq0.x, g0.x); g0.y = fmaf(bs, xq0.y, g0.y);
                g0.z = fmaf(bs, xq0.z, g0.z); g0.w = fmaf(bs, xq0.w, g0.w);
                g1.x = fmaf(bs, xq1.x, g1.x); g1.y = fmaf(bs, xq1.y, g1.y);
                g1.z = fmaf(bs, xq1.z, g1.z); g1.w = fmaf(bs, xq1.w, g1.w);
                g2.x = fmaf(bs, xq2.x, g2.x); g2.y = fmaf(bs, xq2.y, g2.y);
                g2.z = fmaf(bs, xq2.z, g2.z); g2.w = fmaf(bs, xq2.w, g2.w);
                g3.x = fmaf(bs, xq3.x, g3.x); g3.y = fmaf(bs, xq3.y, g3.y);
                g3.z = fmaf(bs, xq3.z, g3.z); g3.w = fmaf(bs, xq3.w, g3.w);
                r = rn; rn = rnn;
                xq0 = xn0; xq1 = xn1; xq2 = xn2; xq3 = xn3;
            }
        }
    }

    // combine the two edge-groups (lanes sub and sub^8 share kernel h)
    g0.x += __shfl_xor(g0.x, 8); g0.y += __shfl_xor(g0.y, 8);
    g0.z += __shfl_xor(g0.z, 8); g0.w += __shfl_xor(g0.w, 8);
    g1.x += __shfl_xor(g1.x, 8); g1.y += __shfl_xor(g1.y, 8);
    g1.z += __shfl_xor(g1.z, 8); g1.w += __shfl_xor(g1.w, 8);
    g2.x += __shfl_xor(g2.x, 8); g2.y += __shfl_xor(g2.y, 8);
    g2.z += __shfl_xor(g2.z, 8); g2.w += __shfl_xor(g2.w, 8);
    g3.x += __shfl_xor(g3.x, 8); g3.y += __shfl_xor(g3.y, 8);
    g3.z += __shfl_xor(g3.z, 8); g3.w += __shfl_xor(g3.w, 8);

    // contraction: this lane computes channels [16*grp, 16*grp+16) for kernel h
    float4 o0 = {0,0,0,0}, o1 = {0,0,0,0}, o2 = {0,0,0,0}, o3 = {0,0,0,0};
    const float* wbase = sW + h * WPAD + grp * 16;
#define CONTRACT1(gv, i) { \
        const float4* wr_ = (const float4*)(wbase + (i) * 32); \
        float4 w0 = wr_[0], w1 = wr_[1], w2 = wr_[2], w3 = wr_[3]; \
        o0.x = fmaf(gv, w0.x, o0.x); o0.y = fmaf(gv, w0.y, o0.y); \
        o0.z = fmaf(gv, w0.z, o0.z); o0.w = fmaf(gv, w0.w, o0.w); \
        o1.x = fmaf(gv, w1.x, o1.x); o1.y = fmaf(gv, w1.y, o1.y); \
        o1.z = fmaf(gv, w1.z, o1.z); o1.w = fmaf(gv, w1.w, o1.w); \
        o2.x = fmaf(gv, w2.x, o2.x); o2.y = fmaf(gv, w2.y, o2.y); \
        o2.z = fmaf(gv, w2.z, o2.z); o2.w = fmaf(gv, w2.w, o2.w); \
        o3.x = fmaf(gv, w3.x, o3.x); o3.y = fmaf(gv, w3.y, o3.y); \
        o3.z = fmaf(gv, w3.z, o3.z); o3.w = fmaf(gv, w3.w, o3.w); }
    CONTRACT1(g0.x,  0) CONTRACT1(g0.y,  1) CONTRACT1(g0.z,  2) CONTRACT1(g0.w,  3)
    CONTRACT1(g1.x,  4) CONTRACT1(g1.y,  5) CONTRACT1(g1.z,  6) CONTRACT1(g1.w,  7)
    CONTRACT1(g2.x,  8) CONTRACT1(g2.y,  9) CONTRACT1(g2.z, 10) CONTRACT1(g2.w, 11)
    CONTRACT1(g3.x, 12) CONTRACT1(g3.y, 13) CONTRACT1(g3.z, 14) CONTRACT1(g3.w, 15)
#undef CONTRACT1

    float inv = 1.f / (float)(deg > 0 ? deg : 1);
    o0.x *= inv; o0.y *= inv; o0.z *= inv; o0.w *= inv;
    o1.x *= inv; o1.y *= inv; o1.z *= inv; o1.w *= inv;
    o2.x *= inv; o2.y *= inv; o2.z *= inv; o2.w *= inv;
    o3.x *= inv; o3.y *= inv; o3.z *= inv; o3.w *= inv;

    // reduce-scatter across the 8 h-lanes: 16 -> 8 -> 4 -> 2 channels
    bool hi4 = (h & 4) != 0;
    float4 k0, k1, s0, s1;
    k0 = hi4 ? o2 : o0; k1 = hi4 ? o3 : o1;
    s0 = hi4 ? o0 : o2; s1 = hi4 ? o1 : o3;
    k0.x += __shfl_xor(s0.x, 4); k0.y += __shfl_xor(s0.y, 4);
    k0.z += __shfl_xor(s0.z, 4); k0.w += __shfl_xor(s0.w, 4);
    k1.x += __shfl_xor(s1.x, 4); k1.y += __shfl_xor(s1.y, 4);
    k1.z += __shfl_xor(s1.z, 4); k1.w += __shfl_xor(s1.w, 4);

    bool hi2 = (h & 2) != 0;
    float4 m0 = hi2 ? k1 : k0;
    float4 sm = hi2 ? k0 : k1;
    m0.x += __shfl_xor(sm.x, 2); m0.y += __shfl_xor(sm.y, 2);
    m0.z += __shfl_xor(sm.z, 2); m0.w += __shfl_xor(sm.w, 2);

    bool hi1 = (h & 1) != 0;
    float e0 = hi1 ? m0.z : m0.x;
    float e1 = hi1 ? m0.w : m0.y;
    float sa = hi1 ? m0.x : m0.z;
    float sb_ = hi1 ? m0.y : m0.w;
    e0 += __shfl_xor(sa, 1);
    e1 += __shfl_xor(sb_, 1);
    // lane now owns channels c0 = 2*sub, c0+1

    int c0 = 2 * sub;
    if (valid) {
        const float4* xr = (const float4*)x + (size_t)n * 4;
        float4 r0 = xr[0], r1 = xr[1], r2 = xr[2], r3 = xr[3];
#define ROOT1(xv, i) { \
            float2 w = *(const float2*)(sWr + (i) * 32 + c0); \
            e0 = fmaf(xv, w.x, e0); e1 = fmaf(xv, w.y, e1); }
        ROOT1(r0.x,  0) ROOT1(r0.y,  1) ROOT1(r0.z,  2) ROOT1(r0.w,  3)
        ROOT1(r1.x,  4) ROOT1(r1.y,  5) ROOT1(r1.z,  6) ROOT1(r1.w,  7)
        ROOT1(r2.x,  8) ROOT1(r2.y,  9) ROOT1(r2.z, 10) ROOT1(r2.w, 11)
        ROOT1(r3.x, 12) ROOT1(r3.y, 13) ROOT1(r3.z, 14) ROOT1(r3.w, 15)
#undef ROOT1
    }

    float2 bb = *(const float2*)(sB + c0);
    e0 += bb.x; e1 += bb.y;
    e0 = e0 > 0.f ? e0 : (__expf(e0) - 1.f);
    e1 = e1 > 0.f ? e1 : (__expf(e1) - 1.f);

    if (valid) *(float2*)(out + (size_t)n * D_OUT + c0) = make_float2(e0, e1);

    // block-level batch stats (NO global atomics)
    float ss0 = valid ? e0 : 0.f, ss1 = valid ? e1 : 0.f;
    float q0 = ss0 * ss0, q1 = ss1 * ss1;
    ss0 += __shfl_xor(ss0, 16); ss1 += __shfl_xor(ss1, 16);
    q0  += __shfl_xor(q0, 16);  q1  += __shfl_xor(q1, 16);
    ss0 += __shfl_xor(ss0, 32); ss1 += __shfl_xor(ss1, 32);
    q0  += __shfl_xor(q0, 32);  q1  += __shfl_xor(q1, 32);
    if ((threadIdx.x & 63) < 16)
        sStats[threadIdx.x >> 6][sub] = make_float4(ss0, ss1, q0, q1);
    __syncthreads();
    if (threadIdx.x < 64) {
        const float* sf = (const float*)sStats;
        float v = sf[threadIdx.x] + sf[64 + threadIdx.x] +
                  sf[128 + threadIdx.x] + sf[192 + threadIdx.x];
        int ssub = threadIdx.x >> 2, comp = threadIdx.x & 3;
        int col = 2 * ssub + (comp & 1) + 32 * (comp >> 1);  // 0..31 sum, 32..63 sumsq
        partials[(size_t)blockIdx.x * 64 + col] = v;
    }
}

// ---------------- stats reduction + batchnorm (two-level, R8-proven) ----------------

__global__ void k_red1(const float* __restrict__ partials, float* __restrict__ partials2,
                       int nrows) {
    __shared__ float sd[4][64];
    int col = threadIdx.x & 63, j = threadIdx.x >> 6;
    float v = 0.f;
    for (int k = 0; k < 16; k++) {
        int r = blockIdx.x * 64 + j * 16 + k;
        if (r < nrows) v += partials[(size_t)r * 64 + col];
    }
    sd[j][col] = v;
    __syncthreads();
    if (threadIdx.x < 64)
        partials2[(size_t)blockIdx.x * 64 + threadIdx.x] =
            sd[0][threadIdx.x] + sd[1][threadIdx.x] + sd[2][threadIdx.x] + sd[3][threadIdx.x];
}

__global__ void k_bnfin(const float* __restrict__ partials2, const float* __restrict__ gamma,
                        const float* __restrict__ beta, float* __restrict__ stats,
                        int nrows2, int N) {
    __shared__ float sd[2][64];
    int col = threadIdx.x & 63, j = threadIdx.x >> 6;   // 128 threads
    float v = 0.f;
    for (int r = j; r < nrows2; r += 2) v += partials2[(size_t)r * 64 + col];
    sd[j][col] = v;
    __syncthreads();
    if (threadIdx.x < 32) {
        int c = threadIdx.x;
        float S = sd[0][c] + sd[1][c];
        float Q = sd[0][32 + c] + sd[1][32 + c];
        float mean = S / (float)N;
        float var  = Q / (float)N - mean * mean;
        float sc   = gamma[c] * rsqrtf(var + 1e-5f);
        stats[c]      = sc;                    // scale
        stats[32 + c] = beta[c] - mean * sc;   // shift
    }
}

__global__ void k_bnapply(float* __restrict__ out, const float* __restrict__ stats, int total4) {
    int i = blockIdx.x * TPB + threadIdx.x;
    if (i < total4) {
        float4 v = ((float4*)out)[i];
        int c0 = (i * 4) & (D_OUT - 1);
        v.x = v.x * stats[c0 + 0] + stats[32 + c0 + 0];
        v.y = v.y * stats[c0 + 1] + stats[32 + c0 + 1];
        v.z = v.z * stats[c0 + 2] + stats[32 + c0 + 2];
        v.w = v.w * stats[c0 + 3] + stats[32 + c0 + 3];
        ((float4*)out)[i] = v;
    }
}

// ---------------- launcher ----------------

extern "C" void kernel_launch(void* const* d_in, const int* in_sizes, int n_in,
                              void* d_out, int out_size, void* d_ws, size_t ws_size,
                              hipStream_t stream) {
    const float* x     = (const float*)d_in[0];
    const int* eidx    = (const int*)d_in[1];
    const float* attr  = (const float*)d_in[2];
    const float* W     = (const float*)d_in[3];
    const float* Wr    = (const float*)d_in[4];
    const float* bias  = (const float*)d_in[5];
    const float* gamma = (const float*)d_in[6];
    const float* beta  = (const float*)d_in[7];
    float* out = (float*)d_out;

    const int N = in_sizes[0] / D_IN;
    const int E = in_sizes[1] / 2;
    const int* src = eidx;
    const int* dst = eidx + E;

    const int nb  = (N + TPB - 1) / TPB;
    const int gE  = (E + TPB - 1) / TPB;
    const int nsb = (N + SBN - 1) / SBN;
    const int nbAgg = (16 * N + TPB - 1) / TPB;   // 16 lanes per node
    const int nbRed = (nbAgg + 63) / 64;
    const int gC  = (E + CT - 1) / CT;

    // fixed-capacity bucket windows: mean + >=8 sigma slack (binomial, P(overflow)~1e-15)
    int capBase = (E + nsb - 1) / nsb;
    int slack = capBase / 16 > 1024 ? capBase / 16 : 1024;
    int cap = capBase + slack;

    // workspace head
    int* rs          = (int*)d_ws;                     // N
    int* re          = rs + N;                         // N (single-path: also cursor)
    float* partials  = (float*)(re + N);               // nbAgg * 64
    float* partials2 = partials + (size_t)nbAgg * 64;  // nbRed * 64
    float* stats     = partials2 + (size_t)nbRed * 64; // 64
    int* sbase       = (int*)(stats + 64);             // 257
    int* scursor     = sbase + 257;                    // 256
    int* sbcnt       = scursor + 256;                  // 256
    uintptr_t tail   = ((uintptr_t)(sbcnt + 256) + 15) & ~(uintptr_t)15;
    size_t headBytes = tail - (uintptr_t)d_ws;

    size_t recStr      = (size_t)nsb * cap;
    size_t needStrided = headBytes + 2 * recStr * 8;
    size_t needDense   = headBytes + 2 * (size_t)E * 8;
    size_t needSingle  = headBytes + (size_t)E * 8 + ((size_t)N + 2 * (size_t)nb) * 4;

    if (ws_size >= needStrided && nsb <= 256) {
        uint2* rec = (uint2*)tail;
        uint2* tmp = rec + recStr;
        k_init<<<1, 512, 0, stream>>>(sbase, scursor, sbcnt, cap, 1);
        k_coarse<<<gC, TPB, 0, stream>>>(src, dst, attr, sbase, scursor, tmp, E, nsb);
        k_fine2<<<nsb, FTPB, 0, stream>>>(tmp, sbase, scursor, rs, re, rec, N);
        k_agg<<<nbAgg, TPB, 0, stream>>>(x, W, Wr, bias, rs, re, rec, out, partials, N);
    } else if (ws_size >= needDense && nsb <= 256) {
        uint2* rec = (uint2*)tail;
        uint2* tmp = rec + E;
        k_init<<<1, 512, 0, stream>>>(sbase, scursor, sbcnt, cap, 0);
        int gH = min(1024, gE);
        k_sbhist<<<gH, TPB, 0, stream>>>(dst, sbcnt, E);
        k_sbscan<<<1, 256, 0, stream>>>(sbcnt, sbase, nsb);
        k_coarse<<<gC, TPB, 0, stream>>>(src, dst, attr, sbase, scursor, tmp, E, nsb);
        k_fine2<<<nsb, FTPB, 0, stream>>>(tmp, sbase, scursor, rs, re, rec, N);
        k_agg<<<nbAgg, TPB, 0, stream>>>(x, W, Wr, bias, rs, re, rec, out, partials, N);
    } else if (ws_size >= needSingle && nb <= 512) {
        uint2* rec = (uint2*)tail;
        int* cnt   = (int*)(rec + E);
        int* bsum  = cnt + N;
        int* boff  = bsum + nb;
        k_zero<<<nb, TPB, 0, stream>>>(cnt, N);
        k_hist<<<gE, TPB, 0, stream>>>(dst, cnt, E);
        k_scan_a<<<nb, TPB, 0, stream>>>(cnt, bsum, N);
        k_scan_b<<<1, 512, 0, stream>>>(bsum, boff, nb);
        k_scan_c<<<nb, TPB, 0, stream>>>(cnt, boff, rs, re, N);
        k_scatter<<<gE, TPB, 0, stream>>>(src, dst, attr, re, rec, E);
        k_agg<<<nbAgg, TPB, 0, stream>>>(x, W, Wr, bias, rs, re, rec, out, partials, N);
    }

    k_red1<<<nbRed, TPB, 0, stream>>>(partials, partials2, nbAgg);
    k_bnfin<<<1, 128, 0, stream>>>(partials2, gamma, beta, stats, nbRed, N);
    int total4 = N * D_OUT / 4;
    k_bnapply<<<(total4 + TPB - 1) / TPB, TPB, 0, stream>>>(out, stats, total4);
}